// Round 8
// baseline (40.346 us; speedup 1.0000x reference)
//
#include <hip/hip_runtime.h>

// R8: within-round A/B probe at equal work. Kernel A = R6 reg-direct path
// (control, cells [0,half)); kernel B = LDS-coalesced global_load_lds
// two-phase path (cells [half,cells)). Both plain-store block partials into
// d_ws; small reduce kernel sums 3136 partials. rocprof per-dispatch durs
// give the decisive comparison: is the reg-direct path L1-request-
// amplification-bound (B wins) or fabric-bound (B >= A)?

#define LAMBDA_COORD 5.0f
#define LAMBDA_NOOBJ 0.5f

constexpr int C_FIELDS = 30;
constexpr int CELLS_PER_BLOCK = 256;
constexpr int TILE_FLOATS = CELLS_PER_BLOCK * C_FIELDS;  // 7680 floats = 30720 B
constexpr int CHUNKS = (TILE_FLOATS * 4) / 1024;         // 30 x 1024B chunks

// ---------------- Kernel A: reg-direct (R6) ----------------
__global__ __launch_bounds__(256) void yolo_a(
    const float* __restrict__ pred, const float* __restrict__ targ,
    float* __restrict__ part)
{
    __shared__ float red[4];
    const int tid = threadIdx.x;
    const long long cell = (long long)blockIdx.x * 256 + tid;
    const float2* __restrict__ pv = (const float2*)(pred + cell * C_FIELDS);
    const float2* __restrict__ tv = (const float2*)(targ + cell * C_FIELDS);

    float2 P[15], T[15];
    #pragma unroll
    for (int k = 0; k < 15; ++k) P[k] = pv[k];
    #pragma unroll
    for (int k = 0; k < 15; ++k) T[k] = tv[k];
    __builtin_amdgcn_sched_barrier(0);

    const float tx0 = T[0].x, ty0 = T[0].y, tx1 = T[1].x, ty1 = T[1].y;
    const float t4  = T[2].x;
    const float a2 = (tx1 - tx0) * (ty1 - ty0);

    const float ax0 = P[0].x, ay0 = P[0].y, ax1 = P[1].x, ay1 = P[1].y;
    const float conf = P[2].x;
    const float bx0 = P[2].y, by0 = P[3].x, bx1 = P[3].y, by1 = P[4].x;

    const float wA = fmaxf(fminf(ax1, tx1) - fmaxf(ax0, tx0), 0.0f);
    const float hA = fmaxf(fminf(ay1, ty1) - fmaxf(ay0, ty0), 0.0f);
    const float interA = wA * hA;
    const float a1A = (ax1 - ax0) * (ay1 - ay0);
    const float iouA = interA / (a1A + a2 - interA);

    const float wB = fmaxf(fminf(bx1, tx1) - fmaxf(bx0, tx0), 0.0f);
    const float hB = fmaxf(fminf(by1, ty1) - fmaxf(by0, ty0), 0.0f);
    const float interB = wB * hB;
    const float a1B = (bx1 - bx0) * (by1 - by0);
    const float iouB = interB / (a1B + a2 - interB);

    bool pickB;
    if (iouA != iouA)      pickB = false;
    else if (iouB != iouB) pickB = true;
    else                   pickB = (iouB > iouA);

    const float c0 = pickB ? bx0 : ax0;
    const float c1 = pickB ? by0 : ay0;
    const float c2 = pickB ? bx1 : ax1;
    const float c3 = pickB ? by1 : ay1;

    const bool obj = (t4 > 0.0f);

    const float dx = (obj ? c0 : 0.0f) - tx0;
    const float dy = (obj ? c1 : 0.0f) - ty0;
    const float l1 = dx * dx + dy * dy;

    const float stw = sqrtf(tx1);
    const float sth = sqrtf(ty1);
    float l2;
    if (obj) {
        const float d0 = sqrtf(c2) - stw;
        const float d1 = sqrtf(c3) - sth;
        l2 = d0 * d0 + d1 * d1;
    } else {
        l2 = stw * stw + sth * sth;
    }

    const float v3 = (obj ? conf : 0.0f) - t4;
    const float l3 = v3 * v3;
    const float v4 = (obj ? 1.0f : conf) - t4;
    const float l4 = v4 * v4;

    float l5 = 0.0f;
    #pragma unroll
    for (int k = 5; k < 15; ++k) {
        const float va = (obj ? P[k].x : 0.0f) - T[k].x;
        const float vb = (obj ? P[k].y : 0.0f) - T[k].y;
        l5 += va * va + vb * vb;
    }

    float acc = LAMBDA_COORD * (l1 + l2) + l3 + LAMBDA_NOOBJ * l4 + l5;

    #pragma unroll
    for (int off = 32; off >= 1; off >>= 1)
        acc += __shfl_xor(acc, off, 64);
    const int wave = tid >> 6;
    const int lane = tid & 63;
    if (lane == 0) red[wave] = acc;
    __syncthreads();
    if (tid == 0)
        part[blockIdx.x] = red[0] + red[1] + red[2] + red[3];
}

// ---------------- Kernel B: LDS-coalesced two-phase (R2 minus atomics) ----
__global__ __launch_bounds__(256, 5) void yolo_b(
    const float* __restrict__ pred, const float* __restrict__ targ,
    float* __restrict__ part, long long cell0, int part0)
{
    __shared__ float sbuf[TILE_FLOATS];
    __shared__ float red[4];

    const int tid = threadIdx.x;
    const int wave = tid >> 6;
    const int lane = tid & 63;
    const long long base = (cell0 + (long long)blockIdx.x * CELLS_PER_BLOCK) * C_FIELDS;

    // Phase 1: stage TARGET tile (perfectly coalesced, direct-to-LDS).
    #pragma unroll
    for (int c = wave; c < CHUNKS; c += 4) {
        const float* g = targ + base + c * 256 + lane * 4;
        __builtin_amdgcn_global_load_lds(
            (const __attribute__((address_space(1))) unsigned int*)g,
            (__attribute__((address_space(3))) unsigned int*)&sbuf[c * 256],
            16, 0, 0);
    }
    __syncthreads();

    const float* t = sbuf + tid * C_FIELDS;
    const float tx0 = t[0], ty0 = t[1], tx1 = t[2], ty1 = t[3], t4 = t[4];
    float tc[20];
    #pragma unroll
    for (int f = 0; f < 20; ++f) tc[f] = t[10 + f];
    __syncthreads();

    // Phase 2: stage PRED tile into the same buffer.
    #pragma unroll
    for (int c = wave; c < CHUNKS; c += 4) {
        const float* g = pred + base + c * 256 + lane * 4;
        __builtin_amdgcn_global_load_lds(
            (const __attribute__((address_space(1))) unsigned int*)g,
            (__attribute__((address_space(3))) unsigned int*)&sbuf[c * 256],
            16, 0, 0);
    }
    __syncthreads();

    const float* p = sbuf + tid * C_FIELDS;
    const float a2 = (tx1 - tx0) * (ty1 - ty0);

    const float ax0 = p[0], ay0 = p[1], ax1 = p[2], ay1 = p[3];
    const float conf = p[4];
    const float bx0 = p[5], by0 = p[6], bx1 = p[7], by1 = p[8];

    const float wA = fmaxf(fminf(ax1, tx1) - fmaxf(ax0, tx0), 0.0f);
    const float hA = fmaxf(fminf(ay1, ty1) - fmaxf(ay0, ty0), 0.0f);
    const float interA = wA * hA;
    const float a1A = (ax1 - ax0) * (ay1 - ay0);
    const float iouA = interA / (a1A + a2 - interA);

    const float wB = fmaxf(fminf(bx1, tx1) - fmaxf(bx0, tx0), 0.0f);
    const float hB = fmaxf(fminf(by1, ty1) - fmaxf(by0, ty0), 0.0f);
    const float interB = wB * hB;
    const float a1B = (bx1 - bx0) * (by1 - by0);
    const float iouB = interB / (a1B + a2 - interB);

    bool pickB;
    if (iouA != iouA)      pickB = false;
    else if (iouB != iouB) pickB = true;
    else                   pickB = (iouB > iouA);

    const float c0 = pickB ? bx0 : ax0;
    const float c1 = pickB ? by0 : ay0;
    const float c2 = pickB ? bx1 : ax1;
    const float c3 = pickB ? by1 : ay1;

    const bool obj = (t4 > 0.0f);

    const float dx = (obj ? c0 : 0.0f) - tx0;
    const float dy = (obj ? c1 : 0.0f) - ty0;
    const float l1 = dx * dx + dy * dy;

    const float stw = sqrtf(tx1);
    const float sth = sqrtf(ty1);
    float l2;
    if (obj) {
        const float d0 = sqrtf(c2) - stw;
        const float d1 = sqrtf(c3) - sth;
        l2 = d0 * d0 + d1 * d1;
    } else {
        l2 = stw * stw + sth * sth;
    }

    const float v3 = (obj ? conf : 0.0f) - t4;
    const float l3 = v3 * v3;
    const float v4 = (obj ? 1.0f : conf) - t4;
    const float l4 = v4 * v4;

    float l5 = 0.0f;
    #pragma unroll
    for (int f = 0; f < 20; ++f) {
        const float v = (obj ? p[10 + f] : 0.0f) - tc[f];
        l5 += v * v;
    }

    float acc = LAMBDA_COORD * (l1 + l2) + l3 + LAMBDA_NOOBJ * l4 + l5;

    #pragma unroll
    for (int off = 32; off >= 1; off >>= 1)
        acc += __shfl_xor(acc, off, 64);
    if (lane == 0) red[wave] = acc;
    __syncthreads();
    if (tid == 0)
        part[part0 + blockIdx.x] = red[0] + red[1] + red[2] + red[3];
}

// ---------------- Final reduce ----------------
__global__ __launch_bounds__(256) void yolo_reduce_kernel(
    const float* __restrict__ part, float* __restrict__ out,
    int n, float inv_b)
{
    __shared__ float red[4];
    const int tid = threadIdx.x;
    float acc = 0.0f;
    for (int i = tid; i < n; i += 256) acc += part[i];
    #pragma unroll
    for (int off = 32; off >= 1; off >>= 1)
        acc += __shfl_xor(acc, off, 64);
    const int wave = tid >> 6;
    const int lane = tid & 63;
    if (lane == 0) red[wave] = acc;
    __syncthreads();
    if (tid == 0)
        out[0] = (red[0] + red[1] + red[2] + red[3]) * inv_b;
}

extern "C" void kernel_launch(void* const* d_in, const int* in_sizes, int n_in,
                              void* d_out, int out_size, void* d_ws, size_t ws_size,
                              hipStream_t stream) {
    const float* pred = (const float*)d_in[0];
    const float* targ = (const float*)d_in[1];
    float* out = (float*)d_out;
    float* part = (float*)d_ws;

    const long long total = (long long)in_sizes[0];     // B*49*30
    const long long cells = total / C_FIELDS;           // 802816
    const long long B = cells / 49;                     // 16384
    const long long half = cells / 2;                   // 401408 (256-multiple)
    const int blocksA = (int)(half / 256);              // 1568
    const int blocksB = (int)((cells - half) / 256);    // 1568
    const float inv_b = 1.0f / (float)B;

    yolo_a<<<blocksA, 256, 0, stream>>>(pred, targ, part);
    yolo_b<<<blocksB, 256, 0, stream>>>(pred, targ, part, half, blocksA);
    yolo_reduce_kernel<<<1, 256, 0, stream>>>(part, out, blocksA + blocksB, inv_b);
}

// Round 9
// 34.693 us; speedup vs baseline: 1.1630x; 1.1630x over previous
//
#include <hip/hip_runtime.h>

// YOLO loss, fused, two-stage reduction (no atomics). REVERT to R6 (best:
// 34.6us) after the R8 A/B probe refuted the L1-amplification theory:
// coalesced LDS staging was ~25% SLOWER than the reg-direct path at equal
// work. The reg-direct stream runs at ~6.2 TB/s blended (FETCH 94MB HBM +
// ~99MB L3) = ~98% of the 6.3 TB/s read-fabric ceiling -> memory roofline.
// Remaining ~3.6us is the reduce dispatch; cooperative launch (R7) fails
// graph capture, and last-block-done needs an equal-cost memset dispatch.

#define LAMBDA_COORD 5.0f
#define LAMBDA_NOOBJ 0.5f

constexpr int C_FIELDS = 30;

__global__ __launch_bounds__(256) void yolo_loss_kernel(
    const float* __restrict__ pred, const float* __restrict__ targ,
    float* __restrict__ part)
{
    __shared__ float red[4];

    const int tid = threadIdx.x;
    const long long cell = (long long)blockIdx.x * 256 + tid;
    const float2* __restrict__ pv = (const float2*)(pred + cell * C_FIELDS); // 8B aligned
    const float2* __restrict__ tv = (const float2*)(targ + cell * C_FIELDS); // 8B aligned

    // Load both 120B cells as 15 aligned float2 each; issue all before use.
    float2 P[15], T[15];
    #pragma unroll
    for (int k = 0; k < 15; ++k) P[k] = pv[k];
    #pragma unroll
    for (int k = 0; k < 15; ++k) T[k] = tv[k];

    __builtin_amdgcn_sched_barrier(0);

    const float tx0 = T[0].x, ty0 = T[0].y, tx1 = T[1].x, ty1 = T[1].y;
    const float t4  = T[2].x;
    const float a2 = (tx1 - tx0) * (ty1 - ty0);

    const float ax0 = P[0].x, ay0 = P[0].y, ax1 = P[1].x, ay1 = P[1].y;
    const float conf = P[2].x;
    const float bx0 = P[2].y, by0 = P[3].x, bx1 = P[3].y, by1 = P[4].x;

    const float wA = fmaxf(fminf(ax1, tx1) - fmaxf(ax0, tx0), 0.0f);
    const float hA = fmaxf(fminf(ay1, ty1) - fmaxf(ay0, ty0), 0.0f);
    const float interA = wA * hA;
    const float a1A = (ax1 - ax0) * (ay1 - ay0);
    const float iouA = interA / (a1A + a2 - interA);

    const float wB = fmaxf(fminf(bx1, tx1) - fmaxf(bx0, tx0), 0.0f);
    const float hB = fmaxf(fminf(by1, ty1) - fmaxf(by0, ty0), 0.0f);
    const float interB = wB * hB;
    const float a1B = (bx1 - bx0) * (by1 - by0);
    const float iouB = interB / (a1B + a2 - interB);

    // np.argmax over 2: NaN acts as max, first index wins ties.
    bool pickB;
    if (iouA != iouA)      pickB = false;
    else if (iouB != iouB) pickB = true;
    else                   pickB = (iouB > iouA);

    const float c0 = pickB ? bx0 : ax0;
    const float c1 = pickB ? by0 : ay0;
    const float c2 = pickB ? bx1 : ax1;
    const float c3 = pickB ? by1 : ay1;

    const bool obj = (t4 > 0.0f);

    // loss1: xy
    const float dx = (obj ? c0 : 0.0f) - tx0;
    const float dy = (obj ? c1 : 0.0f) - ty0;
    const float l1 = dx * dx + dy * dy;

    // loss2: sqrt wh
    const float stw = sqrtf(tx1);
    const float sth = sqrtf(ty1);
    float l2;
    if (obj) {
        const float d0 = sqrtf(c2) - stw;
        const float d1 = sqrtf(c3) - sth;
        l2 = d0 * d0 + d1 * d1;
    } else {
        l2 = stw * stw + sth * sth;
    }

    // loss3 / loss4: conf
    const float v3 = (obj ? conf : 0.0f) - t4;
    const float l3 = v3 * v3;
    const float v4 = (obj ? 1.0f : conf) - t4;
    const float l4 = v4 * v4;

    // loss5: cls fields 10..29 = float2 slots 5..14
    float l5 = 0.0f;
    #pragma unroll
    for (int k = 5; k < 15; ++k) {
        const float va = (obj ? P[k].x : 0.0f) - T[k].x;
        const float vb = (obj ? P[k].y : 0.0f) - T[k].y;
        l5 += va * va + vb * vb;
    }

    float acc = LAMBDA_COORD * (l1 + l2) + l3 + LAMBDA_NOOBJ * l4 + l5;

    #pragma unroll
    for (int off = 32; off >= 1; off >>= 1)
        acc += __shfl_xor(acc, off, 64);

    const int wave = tid >> 6;
    const int lane = tid & 63;
    if (lane == 0) red[wave] = acc;
    __syncthreads();
    if (tid == 0)
        part[blockIdx.x] = red[0] + red[1] + red[2] + red[3];  // plain store
}

__global__ __launch_bounds__(256) void yolo_reduce_kernel(
    const float* __restrict__ part, float* __restrict__ out,
    int n, float inv_b)
{
    __shared__ float red[4];
    const int tid = threadIdx.x;
    float acc = 0.0f;
    const float4* p4 = (const float4*)part;
    for (int i = tid; i < n / 4; i += 256) {
        const float4 v = p4[i];
        acc += v.x + v.y + v.z + v.w;
    }
    #pragma unroll
    for (int off = 32; off >= 1; off >>= 1)
        acc += __shfl_xor(acc, off, 64);
    const int wave = tid >> 6;
    const int lane = tid & 63;
    if (lane == 0) red[wave] = acc;
    __syncthreads();
    if (tid == 0)
        out[0] = (red[0] + red[1] + red[2] + red[3]) * inv_b;
}

extern "C" void kernel_launch(void* const* d_in, const int* in_sizes, int n_in,
                              void* d_out, int out_size, void* d_ws, size_t ws_size,
                              hipStream_t stream) {
    const float* pred = (const float*)d_in[0];
    const float* targ = (const float*)d_in[1];
    float* out = (float*)d_out;
    float* part = (float*)d_ws;                         // 3136 floats

    const long long total = (long long)in_sizes[0];     // B*49*30
    const long long cells = total / C_FIELDS;           // 802816
    const long long B = cells / 49;                     // 16384
    const int blocks = (int)(cells / 256);              // 3136 exact, %4==0
    const float inv_b = 1.0f / (float)B;

    yolo_loss_kernel<<<blocks, 256, 0, stream>>>(pred, targ, part);
    yolo_reduce_kernel<<<1, 256, 0, stream>>>(part, out, blocks, inv_b);
}